// Round 14
// baseline (212.229 us; speedup 1.0000x reference)
//
#include <hip/hip_runtime.h>

constexpr int B = 8, N = 512, E = 65536;
constexpr int D_IN = 128, D_H = 64, R_IN = 32, R_OUT = 32;
constexpr int NT = B * N;
constexpr size_t NN = (size_t)B * N * N;   // 2,097,152
constexpr int CAP = 64;                    // bucket capacity (mean deg 16)

// ---------------------------------------------------------------------------
// setup_pack: blocks 0..511 = bucket-CSR fill (both sides);
//             blocks 512..767 = psi_1 LDS-staged GEMM (32 nodes/block).
// x staged TRANSPOSED xT[k][n] (pad 33): reads at col k hit distinct banks
// ((k+n)%32) instead of all-same-bank k%32 (8-way conflict in prior version).
// ---------------------------------------------------------------------------
__global__ __launch_bounds__(256) void setup_pack(
    const int* __restrict__ src_s, const int* __restrict__ dst_s,
    const float* __restrict__ ea_s,
    const int* __restrict__ src_t, const int* __restrict__ dst_t,
    const float* __restrict__ ea_t,
    int* __restrict__ deg, int2* __restrict__ pack_s, int2* __restrict__ pack_t,
    const float* __restrict__ x_s, const float* __restrict__ x_t,
    const float* __restrict__ Wr, const float* __restrict__ Wn,
    const float* __restrict__ b,
    float* __restrict__ xr, float* __restrict__ xn) {
  __shared__ float xT[D_IN][33];     // 16.9 KB, transposed + padded
  __shared__ float Wb[D_IN][128];    // 64 KB: cols 0..63 = Wr, 64..127 = Wn
  const int bid = blockIdx.x;
  const int tid = threadIdx.x;       // 256

  if (bid < 512) {
    const int gid = bid * 256 + tid;                 // 0..2E-1
    const int side = gid >> 16;
    const int e = gid & (E - 1);
    const int* __restrict__ src = side ? src_t : src_s;
    const int* __restrict__ dst = side ? dst_t : dst_s;
    const float* __restrict__ ea = side ? ea_t : ea_s;
    int2* __restrict__ pack = side ? pack_t : pack_s;
    const int d = dst[e];
    const int slot = atomicAdd(&deg[side * NT + d], 1);
    if (slot < CAP)
      pack[((size_t)d << 6) + slot] = make_int2(src[e], __float_as_int(ea[e]));
    return;
  }

  const int pb = bid - 512;          // 0..255
  const int side = pb >> 7;
  const int n0 = (pb & 127) * 32;
  const float* __restrict__ x = side ? x_t : x_s;

#pragma unroll
  for (int j = 0; j < 4; ++j) {      // stage x transposed: 1024 float4
    const int i = tid + j * 256;
    const int n = i >> 5, k4 = (i & 31) * 4;
    const float4 v = *(const float4*)(x + (size_t)(n0 + n) * D_IN + k4);
    xT[k4 + 0][n] = v.x;
    xT[k4 + 1][n] = v.y;
    xT[k4 + 2][n] = v.z;
    xT[k4 + 3][n] = v.w;
  }
#pragma unroll
  for (int j = 0; j < 8; ++j) {
    const int i = tid + j * 256;
    const int k = i >> 4, c4 = (i & 15) * 4;
    *(float4*)&Wb[k][c4]      = *(const float4*)(Wr + k * D_H + c4);
    *(float4*)&Wb[k][64 + c4] = *(const float4*)(Wn + k * D_H + c4);
  }
  __syncthreads();

  const int c0 = (tid & 31) * 4;
  const int nb = (tid >> 5) * 4;
  float4 bv = make_float4(0.f, 0.f, 0.f, 0.f);
  if (c0 < 64) bv = *(const float4*)(b + c0);
  float4 acc0 = bv, acc1 = bv, acc2 = bv, acc3 = bv;

#pragma unroll 16
  for (int k = 0; k < D_IN; ++k) {
    const float4 w = *(const float4*)&Wb[k][c0];
    const float x0 = xT[k][nb + 0];
    const float x1 = xT[k][nb + 1];
    const float x2 = xT[k][nb + 2];
    const float x3 = xT[k][nb + 3];
    acc0.x += x0 * w.x; acc0.y += x0 * w.y; acc0.z += x0 * w.z; acc0.w += x0 * w.w;
    acc1.x += x1 * w.x; acc1.y += x1 * w.y; acc1.z += x1 * w.z; acc1.w += x1 * w.w;
    acc2.x += x2 * w.x; acc2.y += x2 * w.y; acc2.z += x2 * w.z; acc2.w += x2 * w.w;
    acc3.x += x3 * w.x; acc3.y += x3 * w.y; acc3.z += x3 * w.z; acc3.w += x3 * w.w;
  }

  const size_t gbase = (size_t)(side * NT + n0 + nb);
  if (c0 < 64) {
    *(float4*)(xr + (gbase + 0) * D_H + c0) = acc0;
    *(float4*)(xr + (gbase + 1) * D_H + c0) = acc1;
    *(float4*)(xr + (gbase + 2) * D_H + c0) = acc2;
    *(float4*)(xr + (gbase + 3) * D_H + c0) = acc3;
  } else {
    const int c = c0 - 64;
    *(float4*)(xn + (gbase + 0) * D_H + c) = acc0;
    *(float4*)(xn + (gbase + 1) * D_H + c) = acc1;
    *(float4*)(xn + (gbase + 2) * D_H + c) = acc2;
    *(float4*)(xn + (gbase + 3) * D_H + c) = acc3;
  }
}

// ---------------------------------------------------------------------------
// agg_pack: blocks 0..511 = gather64 + h = relu(xr + agg) materialization;
//           blocks 512..1535 = s-side gather32+psi2+Wm1 for BOTH steps.
// ---------------------------------------------------------------------------
__global__ __launch_bounds__(256) void agg_pack(
    const float* __restrict__ xn, const float* __restrict__ xr,
    const int* __restrict__ deg,
    const int2* __restrict__ pack_s, const int2* __restrict__ pack_t,
    float* __restrict__ h,
    const float* __restrict__ r_all,
    const float* __restrict__ W2r, const float* __restrict__ W2n,
    const float* __restrict__ b2,
    const float* __restrict__ Wm1, const float* __restrict__ bm1,
    float* __restrict__ Psb) {
  __shared__ float sh[3 * 8 * 33];   // 3.2 KB (gp2 path)
  const int bid = blockIdx.x;
  const int tid = threadIdx.x;

  if (bid < 512) {
    // ---- gather64 + h materialization ----
    const int gid = bid * 256 + tid;
    const int side = gid >> 16;
    const int local = gid & 65535;
    const int n = local >> 4;
    const int c4 = (local & 15) * 4;
    const int2* __restrict__ pack = side ? pack_t : pack_s;
    const float* __restrict__ xb = xn + (size_t)side * NT * D_H;
    const int cnt = deg[side * NT + n];
    const size_t base = (size_t)n << 6;
    float4 acc = make_float4(0.f, 0.f, 0.f, 0.f);
    for (int k = 0; k < cnt; ++k) {
      const int2 p = pack[base + k];
      const float w = __int_as_float(p.y);
      const float4 v = *(const float4*)(xb + (size_t)p.x * D_H + c4);
      acc.x += v.x * w; acc.y += v.y * w; acc.z += v.z * w; acc.w += v.w * w;
    }
    const size_t oi = ((size_t)side * NT + n) * D_H + c4;
    const float4 rv = *(const float4*)(xr + oi);
    *(float4*)(h + oi) = make_float4(fmaxf(rv.x + acc.x, 0.f), fmaxf(rv.y + acc.y, 0.f),
                                     fmaxf(rv.z + acc.z, 0.f), fmaxf(rv.w + acc.w, 0.f));
    return;
  }

  // ---- gp2 s-side, steps 0 and 1 ----
  float (*agg)[33] = (float(*)[33])sh;
  float (*rr)[33]  = (float(*)[33])(sh + 8 * 33);
  float (*o)[33]   = (float(*)[33])(sh + 16 * 33);
  const int blk = bid - 512;         // 0..1023
  const int st = blk >> 9;
  const int n0 = (blk & 511) * 8;
  const float* __restrict__ r = r_all + (size_t)st * NT * R_IN;
  const int g = tid >> 5, j = tid & 31;
  const int n = n0 + g;
  const int cnt = deg[n];
  const size_t base = (size_t)n << 6;
  float acc = 0.f;
  for (int k = 0; k < cnt; ++k) {
    const int2 p = pack_s[base + k];
    acc += r[(size_t)p.x * R_IN + j] * __int_as_float(p.y);
  }
  agg[g][j] = acc;
  rr[g][j] = r[(size_t)n * R_IN + j];
  __syncthreads();
  float v = b2[j];
#pragma unroll 8
  for (int k = 0; k < 32; ++k)
    v += rr[g][k] * W2r[k * 32 + j] + agg[g][k] * W2n[k * 32 + j];
  o[g][j] = fmaxf(v, 0.f);
  __syncthreads();
  float p2 = bm1[j];
#pragma unroll 8
  for (int k = 0; k < 32; ++k) p2 += o[g][k] * Wm1[k * 32 + j];
  Psb[((size_t)st * NT + n) * 32 + j] = p2;
}

// ---------------------------------------------------------------------------
// S_hat0 + fused softmax v5: 512 threads, 256 blocks; float4 k-loop.
// ht/hs padded to 68 (16B-aligned; wave64 b128 at stride 68 is bank-balanced:
// exactly 8 accesses/bank). 6 x b128 per 4 k-iters vs 24 scalar reads before.
// ---------------------------------------------------------------------------
__global__ __launch_bounds__(512) void gemm_sm(const float* __restrict__ h,
                                               float* __restrict__ Shat,
                                               float* __restrict__ S0) {
  __shared__ float hs[16][68];    // 4.35 KB
  __shared__ float ht[256][68];   // 69.6 KB
  const int b = blockIdx.x >> 5;
  const int s0 = (blockIdx.x & 31) * 16;
  const int tid = threadIdx.x;    // 512
  const int sg = tid >> 6;        // wave 0..7 -> s-rows 2sg, 2sg+1
  const int tg = tid & 63;
  const float* __restrict__ h_t = h + (size_t)NT * D_H;

  if (tid < 256) {
    const int r = tid >> 4, c4 = (tid & 15) * 4;
    *(float4*)&hs[r][c4] =
        *(const float4*)(h + ((size_t)(b * N + s0 + r)) * D_H + c4);
  }

  float l[2][4][2];
#pragma unroll
  for (int ch = 0; ch < 2; ++ch) {
    __syncthreads();
#pragma unroll
    for (int jj = 0; jj < 8; ++jj) {   // stage ht: 4096 float4 / 512 thr
      const int i = tid + jj * 512;
      const int r = i >> 4, c4 = (i & 15) * 4;
      *(float4*)&ht[r][c4] =
          *(const float4*)(h_t + ((size_t)(b * N + ch * 256 + r)) * D_H + c4);
    }
    __syncthreads();
    float a[4][2];
#pragma unroll
    for (int j = 0; j < 4; ++j) { a[j][0] = 0.f; a[j][1] = 0.f; }
#pragma unroll
    for (int k = 0; k < D_H; k += 4) {
      const float4 h0 = *(const float4*)&hs[sg * 2 + 0][k];
      const float4 h1 = *(const float4*)&hs[sg * 2 + 1][k];
      const float4 t0 = *(const float4*)&ht[tg][k];
      const float4 t1 = *(const float4*)&ht[tg + 64][k];
      const float4 t2 = *(const float4*)&ht[tg + 128][k];
      const float4 t3 = *(const float4*)&ht[tg + 192][k];
      a[0][0] += h0.x * t0.x + h0.y * t0.y + h0.z * t0.z + h0.w * t0.w;
      a[0][1] += h1.x * t0.x + h1.y * t0.y + h1.z * t0.z + h1.w * t0.w;
      a[1][0] += h0.x * t1.x + h0.y * t1.y + h0.z * t1.z + h0.w * t1.w;
      a[1][1] += h1.x * t1.x + h1.y * t1.y + h1.z * t1.z + h1.w * t1.w;
      a[2][0] += h0.x * t2.x + h0.y * t2.y + h0.z * t2.z + h0.w * t2.w;
      a[2][1] += h1.x * t2.x + h1.y * t2.y + h1.z * t2.z + h1.w * t2.w;
      a[3][0] += h0.x * t3.x + h0.y * t3.y + h0.z * t3.z + h0.w * t3.w;
      a[3][1] += h1.x * t3.x + h1.y * t3.y + h1.z * t3.z + h1.w * t3.w;
    }
#pragma unroll
    for (int j = 0; j < 4; ++j) {
      l[ch][j][0] = a[j][0];
      l[ch][j][1] = a[j][1];
    }
  }

  // softmax per s-row (2 rows per wave, full row within the 64 lanes)
  float m[2], inv[2];
#pragma unroll
  for (int i = 0; i < 2; ++i) {
    float mm = -3.4e38f;
#pragma unroll
    for (int ch = 0; ch < 2; ++ch)
#pragma unroll
      for (int j = 0; j < 4; ++j) mm = fmaxf(mm, l[ch][j][i]);
#pragma unroll
    for (int o = 32; o; o >>= 1) mm = fmaxf(mm, __shfl_xor(mm, o));
    m[i] = mm;
  }
#pragma unroll
  for (int i = 0; i < 2; ++i) {
    float ss = 0.f;
#pragma unroll
    for (int ch = 0; ch < 2; ++ch)
#pragma unroll
      for (int j = 0; j < 4; ++j) ss += __expf(l[ch][j][i] - m[i]);
#pragma unroll
    for (int o = 32; o; o >>= 1) ss += __shfl_xor(ss, o);
    inv[i] = 1.0f / ss;
  }
#pragma unroll
  for (int i = 0; i < 2; ++i) {
    const size_t rowb = ((size_t)b * N + s0 + sg * 2 + i) * N;
#pragma unroll
    for (int ch = 0; ch < 2; ++ch)
#pragma unroll
      for (int j = 0; j < 4; ++j) {
        const int t = ch * 256 + j * 64 + tg;
        const float lv = l[ch][j][i];
        Shat[rowb + t] = lv;
        S0[rowb + t] = __expf(lv - m[i]) * inv[i];
      }
  }
}

// ---------------------------------------------------------------------------
// r_t partials over 8 s-octants (serial depth 2). grid (16, 8, B) = 1024.
// STATS=0: Sdata = probabilities. STATS=1: logits + rowM/rowInv.
// ---------------------------------------------------------------------------
template <int STATS>
__global__ void rt_part_k(const float* __restrict__ Sdata,
                          const float* __restrict__ rowM, const float* __restrict__ rowInv,
                          const float* __restrict__ rs, float* __restrict__ part) {
  __shared__ float Ss[32][33];
  __shared__ float Rs[32][32];
  const int b = blockIdx.z;
  const int sq = blockIdx.y;     // 0..7
  const int t0 = blockIdx.x * 32;
  const float* Sb = Sdata + (size_t)b * N * N;
  const float* rb = rs + (size_t)b * N * R_IN;
  const int tid = threadIdx.x;   // 256
  const int lt = tid >> 3;       // 0..31
  const int r0 = (tid & 7) * 4;  // 4 r per thread
  float a0 = 0, a1 = 0, a2 = 0, a3 = 0;
  for (int c = 0; c < 2; ++c) {
    const int s0 = sq * 64 + c * 32;
    for (int i = tid; i < 1024; i += 256) {
      const int ss = i >> 5, cc = i & 31;
      float v = Sb[(size_t)(s0 + ss) * N + t0 + cc];
      if (STATS) {
        const int grow = b * N + s0 + ss;
        v = __expf(v - rowM[grow]) * rowInv[grow];
      }
      Ss[ss][cc] = v;
      Rs[ss][cc] = rb[(size_t)(s0 + ss) * R_IN + cc];
    }
    __syncthreads();
#pragma unroll 8
    for (int ss = 0; ss < 32; ++ss) {
      const float sv = Ss[ss][lt];
      a0 += sv * Rs[ss][r0 + 0];
      a1 += sv * Rs[ss][r0 + 1];
      a2 += sv * Rs[ss][r0 + 2];
      a3 += sv * Rs[ss][r0 + 3];
    }
    __syncthreads();
  }
  float4* out = (float4*)(part + ((size_t)sq * NT + b * N + t0 + lt) * R_IN + r0);
  *out = make_float4(a0, a1, a2, a3);
}

// rt[i] = sum over 8 partials; 128 blocks x 256 thr x float4
__global__ void rt_reduce8(const float* __restrict__ part, float* __restrict__ rt) {
  const size_t i = ((size_t)blockIdx.x * 256 + threadIdx.x) * 4;
  float4 a = *(const float4*)(part + i);
#pragma unroll
  for (int p = 1; p < 8; ++p) {
    const float4 v = *(const float4*)(part + (size_t)p * NT * R_IN + i);
    a.x += v.x; a.y += v.y; a.z += v.z; a.w += v.w;
  }
  *(float4*)(rt + i) = a;
}

// ---------------------------------------------------------------------------
// t-side gather32+psi2+Wm1 with the batch's rt AND pack slots staged in LDS.
// ---------------------------------------------------------------------------
__global__ __launch_bounds__(256) void gp2t(
    const float* __restrict__ rt_b,
    const int* __restrict__ degp, const int2* __restrict__ pack,
    const float* __restrict__ W2r, const float* __restrict__ W2n,
    const float* __restrict__ b2,
    const float* __restrict__ Wm1, const float* __restrict__ bm1,
    float* __restrict__ Pout) {
  __shared__ float rtb[512][32];     // 64 KB: whole batch's r_t
  __shared__ int2 pck[512];          // 4 KB: this block's 8 nodes' slots
  __shared__ float ag[8][33], rr[8][33], o[8][33];
  const int n0 = blockIdx.x * 8;     // 512 blocks
  const int bb = n0 >> 9;            // batch
  const int tid = threadIdx.x;       // 256

  for (int i = tid; i < 4096; i += 256) {
    const int row = i >> 3, k4 = (i & 7) * 4;
    *(float4*)&rtb[row][k4] =
        *(const float4*)(rt_b + ((size_t)(bb * N) + row) * R_IN + k4);
  }
  for (int i = tid; i < 512; i += 256) pck[i] = pack[(size_t)n0 * CAP + i];
  __syncthreads();

  const int g = tid >> 5, j = tid & 31;
  const int n = n0 + g;
  const int cnt = degp[n];
  float acc = 0.f;
  for (int k = 0; k < cnt; ++k) {
    const int2 p = pck[g * CAP + k];
    acc += rtb[p.x & 511][j] * __int_as_float(p.y);
  }
  ag[g][j] = acc;
  rr[g][j] = rtb[n & 511][j];
  __syncthreads();
  float v = b2[j];
#pragma unroll 8
  for (int k = 0; k < 32; ++k)
    v += rr[g][k] * W2r[k * 32 + j] + ag[g][k] * W2n[k * 32 + j];
  o[g][j] = fmaxf(v, 0.f);
  __syncthreads();
  float p2 = 0.f;   // t-side: no bm1
#pragma unroll 8
  for (int k = 0; k < 32; ++k) p2 += o[g][k] * Wm1[k * 32 + j];
  Pout[(size_t)n * 32 + j] = p2;
}

// ---------------------------------------------------------------------------
// Consensus update + softmax v3: 16 s-rows per 512-thread block (256 blocks)
// halves Pt staging traffic. LAST=0: logits + row stats. LAST=1: S only.
// ---------------------------------------------------------------------------
template <int LAST>
__global__ __launch_bounds__(512) void update_sm2(
    const float* __restrict__ Ps, const float* __restrict__ Pt,
    const float* __restrict__ Wm2, const float* __restrict__ bm2,
    float* __restrict__ Shat, float* __restrict__ S,
    float* __restrict__ rowM, float* __restrict__ rowInv) {
  __shared__ float pt4[128][36];     // 18 KB
  const int row0 = blockIdx.x * 16;  // 256 blocks
  const int b = row0 >> 9;
  const int tid = threadIdx.x;       // 512
  const int s_loc = tid >> 5;        // 0..15
  const int lane_t = tid & 31;       // 0..31
  const int row = row0 + s_loc;

  float ps[32], w2v[32];
#pragma unroll
  for (int q = 0; q < 8; ++q) {
    const float4 v = *(const float4*)(Ps + (size_t)row * 32 + q * 4);
    ps[q * 4 + 0] = v.x; ps[q * 4 + 1] = v.y; ps[q * 4 + 2] = v.z; ps[q * 4 + 3] = v.w;
    const float4 w = *(const float4*)(Wm2 + q * 4);
    w2v[q * 4 + 0] = w.x; w2v[q * 4 + 1] = w.y; w2v[q * 4 + 2] = w.z; w2v[q * 4 + 3] = w.w;
  }
  const float bb = bm2[0];

  float l[16];
#pragma unroll
  for (int c = 0; c < 4; ++c) {      // t chunks of 128
    __syncthreads();
#pragma unroll
    for (int j = 0; j < 2; ++j) {    // stage Pt chunk: 1024 float4 / 512 thr
      const int i = tid + j * 512;
      const int t = i >> 3, k4 = (i & 7) * 4;
      const float4 v = *(const float4*)(Pt + ((size_t)(b * N) + c * 128 + t) * 32 + k4);
      *(float4*)&pt4[t][k4] = v;
    }
    __syncthreads();
#pragma unroll
    for (int q = 0; q < 4; ++q) {
      const int tq = q * 32 + lane_t;
      float d = 0.f;
#pragma unroll
      for (int k4 = 0; k4 < 8; ++k4) {
        const float4 pv = *(const float4*)&pt4[tq][k4 * 4];
        d += fmaxf(ps[k4 * 4 + 0] - pv.x, 0.f) * w2v[k4 * 4 + 0];
        d += fmaxf(ps[k4 * 4 + 1] - pv.y, 0.f) * w2v[k4 * 4 + 1];
        d += fmaxf(ps[k4 * 4 + 2] - pv.z, 0.f) * w2v[k4 * 4 + 2];
        d += fmaxf(ps[k4 * 4 + 3] - pv.w, 0.f) * w2v[k4 * 4 + 3];
      }
      const int t = c * 128 + q * 32 + lane_t;
      l[c * 4 + q] = Shat[(size_t)row * N + t] + d + bb;
    }
  }

  float m = l[0];
#pragma unroll
  for (int i = 1; i < 16; ++i) m = fmaxf(m, l[i]);
#pragma unroll
  for (int o = 16; o; o >>= 1) m = fmaxf(m, __shfl_xor(m, o));
  float sum = 0.f;
#pragma unroll
  for (int i = 0; i < 16; ++i) sum += __expf(l[i] - m);
#pragma unroll
  for (int o = 16; o; o >>= 1) sum += __shfl_xor(sum, o);
  const float inv = 1.0f / sum;

  if (!LAST) {
#pragma unroll
    for (int c = 0; c < 4; ++c)
#pragma unroll
      for (int q = 0; q < 4; ++q) {
        const int t = c * 128 + q * 32 + lane_t;
        Shat[(size_t)row * N + t] = l[c * 4 + q];
      }
    if (lane_t == 0) { rowM[row] = m; rowInv[row] = inv; }
  } else {
#pragma unroll
    for (int c = 0; c < 4; ++c)
#pragma unroll
      for (int q = 0; q < 4; ++q) {
        const int t = c * 128 + q * 32 + lane_t;
        S[(size_t)row * N + t] = __expf(l[c * 4 + q] - m) * inv;
      }
  }
}

// ---------------------------------------------------------------------------
extern "C" void kernel_launch(void* const* d_in, const int* in_sizes, int n_in,
                              void* d_out, int out_size, void* d_ws, size_t ws_size,
                              hipStream_t stream) {
  const float* x_s  = (const float*)d_in[0];
  const int*   ei_s = (const int*)d_in[1];
  const float* ea_s = (const float*)d_in[2];
  const float* x_t  = (const float*)d_in[4];
  const int*   ei_t = (const int*)d_in[5];
  const float* ea_t = (const float*)d_in[6];
  const float* r_all = (const float*)d_in[8];
  const float* W1r = (const float*)d_in[9];
  const float* W1n = (const float*)d_in[10];
  const float* b1  = (const float*)d_in[11];
  const float* W2r = (const float*)d_in[12];
  const float* W2n = (const float*)d_in[13];
  const float* b2  = (const float*)d_in[14];
  const float* Wm1 = (const float*)d_in[15];
  const float* bm1 = (const float*)d_in[16];
  const float* Wm2 = (const float*)d_in[17];
  const float* bm2 = (const float*)d_in[18];

  const int* src_s = ei_s;
  const int* dst_s = ei_s + E;
  const int* src_t = ei_t;
  const int* dst_t = ei_t + E;

  float* ws = (float*)d_ws;
  float* xr   = ws; ws += (size_t)2 * NT * D_H;
  float* xn   = ws; ws += (size_t)2 * NT * D_H;
  float* h    = ws; ws += (size_t)2 * NT * D_H;
  float* Shat = ws; ws += NN;
  float* rt_p = ws; ws += (size_t)8 * NT * R_IN;
  float* rt_b = ws; ws += (size_t)NT * R_IN;
  float* Psb  = ws; ws += (size_t)2 * NT * R_OUT;
  float* Ptb  = ws; ws += (size_t)NT * R_OUT;
  float* rowM = ws; ws += NT;
  float* rowI = ws; ws += NT;
  int* deg      = (int*)ws; ws += 2 * NT;
  int2* pack_s  = (int2*)ws; ws += (size_t)NT * CAP * 2;
  int2* pack_t  = (int2*)ws; ws += (size_t)NT * CAP * 2;

  float* S0_out = (float*)d_out;
  float* SL_out = S0_out + NN;

  // setup
  hipMemsetAsync(deg, 0, 2 * NT * sizeof(int), stream);
  setup_pack<<<768, 256, 0, stream>>>(src_s, dst_s, ea_s, src_t, dst_t, ea_t,
                                      deg, pack_s, pack_t,
                                      x_s, x_t, W1r, W1n, b1, xr, xn);
  agg_pack<<<1536, 256, 0, stream>>>(xn, xr, deg, pack_s, pack_t, h,
                                     r_all, W2r, W2n, b2, Wm1, bm1, Psb);
  gemm_sm<<<256, 512, 0, stream>>>(h, Shat, S0_out);

  // step 0
  rt_part_k<0><<<dim3(16, 8, B), 256, 0, stream>>>(S0_out, nullptr, nullptr, r_all, rt_p);
  rt_reduce8<<<128, 256, 0, stream>>>(rt_p, rt_b);
  gp2t<<<512, 256, 0, stream>>>(rt_b, deg + NT, pack_t, W2r, W2n, b2, Wm1, bm1, Ptb);
  update_sm2<0><<<256, 512, 0, stream>>>(Psb, Ptb, Wm2, bm2, Shat, nullptr, rowM, rowI);

  // step 1
  rt_part_k<1><<<dim3(16, 8, B), 256, 0, stream>>>(Shat, rowM, rowI,
                                                   r_all + (size_t)NT * R_IN, rt_p);
  rt_reduce8<<<128, 256, 0, stream>>>(rt_p, rt_b);
  gp2t<<<512, 256, 0, stream>>>(rt_b, deg + NT, pack_t, W2r, W2n, b2, Wm1, bm1, Ptb);
  update_sm2<1><<<256, 512, 0, stream>>>(Psb + (size_t)NT * R_OUT, Ptb, Wm2, bm2,
                                         Shat, SL_out, nullptr, nullptr);
}

// Round 15
// 200.030 us; speedup vs baseline: 1.0610x; 1.0610x over previous
//
#include <hip/hip_runtime.h>

constexpr int B = 8, N = 512, E = 65536;
constexpr int D_IN = 128, D_H = 64, R_IN = 32, R_OUT = 32;
constexpr int NT = B * N;
constexpr size_t NN = (size_t)B * N * N;   // 2,097,152
constexpr int CAP = 64;                    // bucket capacity (mean deg 16)

// ---------------------------------------------------------------------------
// setup_pack: blocks 0..511 = bucket-CSR fill (both sides);
//             blocks 512..767 = psi_1 LDS-staged GEMM (32 nodes/block).
// ---------------------------------------------------------------------------
__global__ __launch_bounds__(256) void setup_pack(
    const int* __restrict__ src_s, const int* __restrict__ dst_s,
    const float* __restrict__ ea_s,
    const int* __restrict__ src_t, const int* __restrict__ dst_t,
    const float* __restrict__ ea_t,
    int* __restrict__ deg, int2* __restrict__ pack_s, int2* __restrict__ pack_t,
    const float* __restrict__ x_s, const float* __restrict__ x_t,
    const float* __restrict__ Wr, const float* __restrict__ Wn,
    const float* __restrict__ b,
    float* __restrict__ xr, float* __restrict__ xn) {
  __shared__ float smem[32 * D_IN + D_IN * 128];   // 80 KB (psi1 path only)
  const int bid = blockIdx.x;
  const int tid = threadIdx.x;       // 256

  if (bid < 512) {
    const int gid = bid * 256 + tid;                 // 0..2E-1
    const int side = gid >> 16;
    const int e = gid & (E - 1);
    const int* __restrict__ src = side ? src_t : src_s;
    const int* __restrict__ dst = side ? dst_t : dst_s;
    const float* __restrict__ ea = side ? ea_t : ea_s;
    int2* __restrict__ pack = side ? pack_t : pack_s;
    const int d = dst[e];
    const int slot = atomicAdd(&deg[side * NT + d], 1);
    if (slot < CAP)
      pack[((size_t)d << 6) + slot] = make_int2(src[e], __float_as_int(ea[e]));
    return;
  }

  float (*xls)[D_IN] = (float(*)[D_IN])smem;               // [32][128]
  float (*Wb)[128]   = (float(*)[128])(smem + 32 * D_IN);  // [128][128]
  const int pb = bid - 512;          // 0..255
  const int side = pb >> 7;
  const int n0 = (pb & 127) * 32;
  const float* __restrict__ x = side ? x_t : x_s;

#pragma unroll
  for (int j = 0; j < 4; ++j) {
    const int i = tid + j * 256;
    const int n = i >> 5, k4 = (i & 31) * 4;
    *(float4*)&xls[n][k4] = *(const float4*)(x + (size_t)(n0 + n) * D_IN + k4);
  }
#pragma unroll
  for (int j = 0; j < 8; ++j) {
    const int i = tid + j * 256;
    const int k = i >> 4, c4 = (i & 15) * 4;
    *(float4*)&Wb[k][c4]      = *(const float4*)(Wr + k * D_H + c4);
    *(float4*)&Wb[k][64 + c4] = *(const float4*)(Wn + k * D_H + c4);
  }
  __syncthreads();

  const int c0 = (tid & 31) * 4;
  const int nb = (tid >> 5) * 4;
  float4 bv = make_float4(0.f, 0.f, 0.f, 0.f);
  if (c0 < 64) bv = *(const float4*)(b + c0);
  float4 acc0 = bv, acc1 = bv, acc2 = bv, acc3 = bv;

#pragma unroll 16
  for (int k = 0; k < D_IN; ++k) {
    const float4 w = *(const float4*)&Wb[k][c0];
    const float x0 = xls[nb + 0][k];
    const float x1 = xls[nb + 1][k];
    const float x2 = xls[nb + 2][k];
    const float x3 = xls[nb + 3][k];
    acc0.x += x0 * w.x; acc0.y += x0 * w.y; acc0.z += x0 * w.z; acc0.w += x0 * w.w;
    acc1.x += x1 * w.x; acc1.y += x1 * w.y; acc1.z += x1 * w.z; acc1.w += x1 * w.w;
    acc2.x += x2 * w.x; acc2.y += x2 * w.y; acc2.z += x2 * w.z; acc2.w += x2 * w.w;
    acc3.x += x3 * w.x; acc3.y += x3 * w.y; acc3.z += x3 * w.z; acc3.w += x3 * w.w;
  }

  const size_t gbase = (size_t)(side * NT + n0 + nb);
  if (c0 < 64) {
    *(float4*)(xr + (gbase + 0) * D_H + c0) = acc0;
    *(float4*)(xr + (gbase + 1) * D_H + c0) = acc1;
    *(float4*)(xr + (gbase + 2) * D_H + c0) = acc2;
    *(float4*)(xr + (gbase + 3) * D_H + c0) = acc3;
  } else {
    const int c = c0 - 64;
    *(float4*)(xn + (gbase + 0) * D_H + c) = acc0;
    *(float4*)(xn + (gbase + 1) * D_H + c) = acc1;
    *(float4*)(xn + (gbase + 2) * D_H + c) = acc2;
    *(float4*)(xn + (gbase + 3) * D_H + c) = acc3;
  }
}

// ---------------------------------------------------------------------------
// agg_pack: blocks 0..511 = gather64 + h = relu(xr + agg) materialization;
//           blocks 512..1535 = s-side gather32+psi2+Wm1 for BOTH steps.
// ---------------------------------------------------------------------------
__global__ __launch_bounds__(256) void agg_pack(
    const float* __restrict__ xn, const float* __restrict__ xr,
    const int* __restrict__ deg,
    const int2* __restrict__ pack_s, const int2* __restrict__ pack_t,
    float* __restrict__ h,
    const float* __restrict__ r_all,
    const float* __restrict__ W2r, const float* __restrict__ W2n,
    const float* __restrict__ b2,
    const float* __restrict__ Wm1, const float* __restrict__ bm1,
    float* __restrict__ Psb) {
  __shared__ float sh[3 * 8 * 33];   // 3.2 KB (gp2 path)
  const int bid = blockIdx.x;
  const int tid = threadIdx.x;

  if (bid < 512) {
    // ---- gather64 + h materialization ----
    const int gid = bid * 256 + tid;
    const int side = gid >> 16;
    const int local = gid & 65535;
    const int n = local >> 4;
    const int c4 = (local & 15) * 4;
    const int2* __restrict__ pack = side ? pack_t : pack_s;
    const float* __restrict__ xb = xn + (size_t)side * NT * D_H;
    const int cnt = deg[side * NT + n];
    const size_t base = (size_t)n << 6;
    float4 acc = make_float4(0.f, 0.f, 0.f, 0.f);
    for (int k = 0; k < cnt; ++k) {
      const int2 p = pack[base + k];
      const float w = __int_as_float(p.y);
      const float4 v = *(const float4*)(xb + (size_t)p.x * D_H + c4);
      acc.x += v.x * w; acc.y += v.y * w; acc.z += v.z * w; acc.w += v.w * w;
    }
    const size_t oi = ((size_t)side * NT + n) * D_H + c4;
    const float4 rv = *(const float4*)(xr + oi);
    *(float4*)(h + oi) = make_float4(fmaxf(rv.x + acc.x, 0.f), fmaxf(rv.y + acc.y, 0.f),
                                     fmaxf(rv.z + acc.z, 0.f), fmaxf(rv.w + acc.w, 0.f));
    return;
  }

  // ---- gp2 s-side, steps 0 and 1 ----
  float (*agg)[33] = (float(*)[33])sh;
  float (*rr)[33]  = (float(*)[33])(sh + 8 * 33);
  float (*o)[33]   = (float(*)[33])(sh + 16 * 33);
  const int blk = bid - 512;         // 0..1023
  const int st = blk >> 9;
  const int n0 = (blk & 511) * 8;
  const float* __restrict__ r = r_all + (size_t)st * NT * R_IN;
  const int g = tid >> 5, j = tid & 31;
  const int n = n0 + g;
  const int cnt = deg[n];
  const size_t base = (size_t)n << 6;
  float acc = 0.f;
  for (int k = 0; k < cnt; ++k) {
    const int2 p = pack_s[base + k];
    acc += r[(size_t)p.x * R_IN + j] * __int_as_float(p.y);
  }
  agg[g][j] = acc;
  rr[g][j] = r[(size_t)n * R_IN + j];
  __syncthreads();
  float v = b2[j];
#pragma unroll 8
  for (int k = 0; k < 32; ++k)
    v += rr[g][k] * W2r[k * 32 + j] + agg[g][k] * W2n[k * 32 + j];
  o[g][j] = fmaxf(v, 0.f);
  __syncthreads();
  float p2 = bm1[j];
#pragma unroll 8
  for (int k = 0; k < 32; ++k) p2 += o[g][k] * Wm1[k * 32 + j];
  Psb[((size_t)st * NT + n) * 32 + j] = p2;
}

// ---------------------------------------------------------------------------
// S_hat0 + fused softmax v4: 512 threads (8 waves = 2/SIMD), 256 blocks.
// Wave sg owns s-rows {2sg, 2sg+1}; per thread 2s x 4t register tile.
// ---------------------------------------------------------------------------
__global__ __launch_bounds__(512) void gemm_sm(const float* __restrict__ h,
                                               float* __restrict__ Shat,
                                               float* __restrict__ S0) {
  __shared__ float hs[16][65];    // 4.1 KB
  __shared__ float ht[256][65];   // 66.6 KB
  const int b = blockIdx.x >> 5;
  const int s0 = (blockIdx.x & 31) * 16;
  const int tid = threadIdx.x;    // 512
  const int sg = tid >> 6;        // wave 0..7 -> s-rows 2sg, 2sg+1
  const int tg = tid & 63;
  const float* __restrict__ h_t = h + (size_t)NT * D_H;

  if (tid < 256) {
    const int r = tid >> 4, c4 = (tid & 15) * 4;
    *(float4*)&hs[r][c4] =
        *(const float4*)(h + ((size_t)(b * N + s0 + r)) * D_H + c4);
  }

  float l[2][4][2];
#pragma unroll
  for (int ch = 0; ch < 2; ++ch) {
    __syncthreads();
#pragma unroll
    for (int jj = 0; jj < 8; ++jj) {   // stage ht: 4096 float4 / 512 thr
      const int i = tid + jj * 512;
      const int r = i >> 4, c4 = (i & 15) * 4;
      *(float4*)&ht[r][c4] =
          *(const float4*)(h_t + ((size_t)(b * N + ch * 256 + r)) * D_H + c4);
    }
    __syncthreads();
    float a[4][2];
#pragma unroll
    for (int j = 0; j < 4; ++j) { a[j][0] = 0.f; a[j][1] = 0.f; }
#pragma unroll 8
    for (int k = 0; k < D_H; ++k) {
      const float t0v = ht[tg][k];
      const float t1v = ht[tg + 64][k];
      const float t2v = ht[tg + 128][k];
      const float t3v = ht[tg + 192][k];
      const float h0 = hs[sg * 2 + 0][k];   // wave-uniform -> broadcast
      const float h1 = hs[sg * 2 + 1][k];
      a[0][0] += h0 * t0v; a[0][1] += h1 * t0v;
      a[1][0] += h0 * t1v; a[1][1] += h1 * t1v;
      a[2][0] += h0 * t2v; a[2][1] += h1 * t2v;
      a[3][0] += h0 * t3v; a[3][1] += h1 * t3v;
    }
#pragma unroll
    for (int j = 0; j < 4; ++j) {
      l[ch][j][0] = a[j][0];
      l[ch][j][1] = a[j][1];
    }
  }

  // softmax per s-row (2 rows per wave, full row within the 64 lanes)
  float m[2], inv[2];
#pragma unroll
  for (int i = 0; i < 2; ++i) {
    float mm = -3.4e38f;
#pragma unroll
    for (int ch = 0; ch < 2; ++ch)
#pragma unroll
      for (int j = 0; j < 4; ++j) mm = fmaxf(mm, l[ch][j][i]);
#pragma unroll
    for (int o = 32; o; o >>= 1) mm = fmaxf(mm, __shfl_xor(mm, o));
    m[i] = mm;
  }
#pragma unroll
  for (int i = 0; i < 2; ++i) {
    float ss = 0.f;
#pragma unroll
    for (int ch = 0; ch < 2; ++ch)
#pragma unroll
      for (int j = 0; j < 4; ++j) ss += __expf(l[ch][j][i] - m[i]);
#pragma unroll
    for (int o = 32; o; o >>= 1) ss += __shfl_xor(ss, o);
    inv[i] = 1.0f / ss;
  }
#pragma unroll
  for (int i = 0; i < 2; ++i) {
    const size_t rowb = ((size_t)b * N + s0 + sg * 2 + i) * N;
#pragma unroll
    for (int ch = 0; ch < 2; ++ch)
#pragma unroll
      for (int j = 0; j < 4; ++j) {
        const int t = ch * 256 + j * 64 + tg;
        const float lv = l[ch][j][i];
        Shat[rowb + t] = lv;
        S0[rowb + t] = __expf(lv - m[i]) * inv[i];
      }
  }
}

// ---------------------------------------------------------------------------
// r_t partials over 8 s-octants (serial depth 2). grid (16, 8, B) = 1024.
// STATS=0: Sdata = probabilities. STATS=1: logits + rowM/rowInv.
// ---------------------------------------------------------------------------
template <int STATS>
__global__ void rt_part_k(const float* __restrict__ Sdata,
                          const float* __restrict__ rowM, const float* __restrict__ rowInv,
                          const float* __restrict__ rs, float* __restrict__ part) {
  __shared__ float Ss[32][33];
  __shared__ float Rs[32][32];
  const int b = blockIdx.z;
  const int sq = blockIdx.y;     // 0..7
  const int t0 = blockIdx.x * 32;
  const float* Sb = Sdata + (size_t)b * N * N;
  const float* rb = rs + (size_t)b * N * R_IN;
  const int tid = threadIdx.x;   // 256
  const int lt = tid >> 3;       // 0..31
  const int r0 = (tid & 7) * 4;  // 4 r per thread
  float a0 = 0, a1 = 0, a2 = 0, a3 = 0;
  for (int c = 0; c < 2; ++c) {
    const int s0 = sq * 64 + c * 32;
    for (int i = tid; i < 1024; i += 256) {
      const int ss = i >> 5, cc = i & 31;
      float v = Sb[(size_t)(s0 + ss) * N + t0 + cc];
      if (STATS) {
        const int grow = b * N + s0 + ss;
        v = __expf(v - rowM[grow]) * rowInv[grow];
      }
      Ss[ss][cc] = v;
      Rs[ss][cc] = rb[(size_t)(s0 + ss) * R_IN + cc];
    }
    __syncthreads();
#pragma unroll 8
    for (int ss = 0; ss < 32; ++ss) {
      const float sv = Ss[ss][lt];
      a0 += sv * Rs[ss][r0 + 0];
      a1 += sv * Rs[ss][r0 + 1];
      a2 += sv * Rs[ss][r0 + 2];
      a3 += sv * Rs[ss][r0 + 3];
    }
    __syncthreads();
  }
  float4* out = (float4*)(part + ((size_t)sq * NT + b * N + t0 + lt) * R_IN + r0);
  *out = make_float4(a0, a1, a2, a3);
}

// rt[i] = sum over 8 partials; 128 blocks x 256 thr x float4
__global__ void rt_reduce8(const float* __restrict__ part, float* __restrict__ rt) {
  const size_t i = ((size_t)blockIdx.x * 256 + threadIdx.x) * 4;
  float4 a = *(const float4*)(part + i);
#pragma unroll
  for (int p = 1; p < 8; ++p) {
    const float4 v = *(const float4*)(part + (size_t)p * NT * R_IN + i);
    a.x += v.x; a.y += v.y; a.z += v.z; a.w += v.w;
  }
  *(float4*)(rt + i) = a;
}

// ---------------------------------------------------------------------------
// t-side gather32+psi2+Wm1 with the batch's rt AND pack slots staged in LDS.
// ---------------------------------------------------------------------------
__global__ __launch_bounds__(256) void gp2t(
    const float* __restrict__ rt_b,
    const int* __restrict__ degp, const int2* __restrict__ pack,
    const float* __restrict__ W2r, const float* __restrict__ W2n,
    const float* __restrict__ b2,
    const float* __restrict__ Wm1, const float* __restrict__ bm1,
    float* __restrict__ Pout) {
  __shared__ float rtb[512][32];     // 64 KB: whole batch's r_t
  __shared__ int2 pck[512];          // 4 KB: this block's 8 nodes' slots
  __shared__ float ag[8][33], rr[8][33], o[8][33];
  const int n0 = blockIdx.x * 8;     // 512 blocks
  const int bb = n0 >> 9;            // batch
  const int tid = threadIdx.x;       // 256

  for (int i = tid; i < 4096; i += 256) {
    const int row = i >> 3, k4 = (i & 7) * 4;
    *(float4*)&rtb[row][k4] =
        *(const float4*)(rt_b + ((size_t)(bb * N) + row) * R_IN + k4);
  }
  for (int i = tid; i < 512; i += 256) pck[i] = pack[(size_t)n0 * CAP + i];
  __syncthreads();

  const int g = tid >> 5, j = tid & 31;
  const int n = n0 + g;
  const int cnt = degp[n];
  float acc = 0.f;
  for (int k = 0; k < cnt; ++k) {
    const int2 p = pck[g * CAP + k];
    acc += rtb[p.x & 511][j] * __int_as_float(p.y);
  }
  ag[g][j] = acc;
  rr[g][j] = rtb[n & 511][j];
  __syncthreads();
  float v = b2[j];
#pragma unroll 8
  for (int k = 0; k < 32; ++k)
    v += rr[g][k] * W2r[k * 32 + j] + ag[g][k] * W2n[k * 32 + j];
  o[g][j] = fmaxf(v, 0.f);
  __syncthreads();
  float p2 = 0.f;   // t-side: no bm1
#pragma unroll 8
  for (int k = 0; k < 32; ++k) p2 += o[g][k] * Wm1[k * 32 + j];
  Pout[(size_t)n * 32 + j] = p2;
}

// ---------------------------------------------------------------------------
// Consensus update + softmax. LAST=0: logits + row stats. LAST=1: S only.
// ---------------------------------------------------------------------------
template <int LAST>
__global__ void update_sm2(const float* __restrict__ Ps, const float* __restrict__ Pt,
                           const float* __restrict__ Wm2, const float* __restrict__ bm2,
                           float* __restrict__ Shat, float* __restrict__ S,
                           float* __restrict__ rowM, float* __restrict__ rowInv) {
  __shared__ float pt4[128][36];     // 18 KB
  const int row0 = blockIdx.x * 8;   // 512 blocks
  const int b = row0 >> 9;
  const int tid = threadIdx.x;       // 256
  const int s_loc = tid >> 5;        // 0..7
  const int lane_t = tid & 31;       // 0..31
  const int row = row0 + s_loc;

  float ps[32], w2v[32];
#pragma unroll
  for (int q = 0; q < 8; ++q) {
    const float4 v = *(const float4*)(Ps + (size_t)row * 32 + q * 4);
    ps[q * 4 + 0] = v.x; ps[q * 4 + 1] = v.y; ps[q * 4 + 2] = v.z; ps[q * 4 + 3] = v.w;
    const float4 w = *(const float4*)(Wm2 + q * 4);
    w2v[q * 4 + 0] = w.x; w2v[q * 4 + 1] = w.y; w2v[q * 4 + 2] = w.z; w2v[q * 4 + 3] = w.w;
  }
  const float bb = bm2[0];

  float l[16];
#pragma unroll
  for (int c = 0; c < 4; ++c) {      // t chunks of 128
    __syncthreads();
#pragma unroll
    for (int j = 0; j < 4; ++j) {
      const int i = tid + j * 256;
      const int t = i >> 3, k4 = (i & 7) * 4;
      const float4 v = *(const float4*)(Pt + ((size_t)(b * N) + c * 128 + t) * 32 + k4);
      *(float4*)&pt4[t][k4] = v;
    }
    __syncthreads();
#pragma unroll
    for (int q = 0; q < 4; ++q) {
      const int tq = q * 32 + lane_t;
      float d = 0.f;
#pragma unroll
      for (int k4 = 0; k4 < 8; ++k4) {
        const float4 pv = *(const float4*)&pt4[tq][k4 * 4];
        d += fmaxf(ps[k4 * 4 + 0] - pv.x, 0.f) * w2v[k4 * 4 + 0];
        d += fmaxf(ps[k4 * 4 + 1] - pv.y, 0.f) * w2v[k4 * 4 + 1];
        d += fmaxf(ps[k4 * 4 + 2] - pv.z, 0.f) * w2v[k4 * 4 + 2];
        d += fmaxf(ps[k4 * 4 + 3] - pv.w, 0.f) * w2v[k4 * 4 + 3];
      }
      const int t = c * 128 + q * 32 + lane_t;
      l[c * 4 + q] = Shat[(size_t)row * N + t] + d + bb;
    }
  }

  float m = l[0];
#pragma unroll
  for (int i = 1; i < 16; ++i) m = fmaxf(m, l[i]);
#pragma unroll
  for (int o = 16; o; o >>= 1) m = fmaxf(m, __shfl_xor(m, o));
  float sum = 0.f;
#pragma unroll
  for (int i = 0; i < 16; ++i) sum += __expf(l[i] - m);
#pragma unroll
  for (int o = 16; o; o >>= 1) sum += __shfl_xor(sum, o);
  const float inv = 1.0f / sum;

  if (!LAST) {
#pragma unroll
    for (int c = 0; c < 4; ++c)
#pragma unroll
      for (int q = 0; q < 4; ++q) {
        const int t = c * 128 + q * 32 + lane_t;
        Shat[(size_t)row * N + t] = l[c * 4 + q];
      }
    if (lane_t == 0) { rowM[row] = m; rowInv[row] = inv; }
  } else {
#pragma unroll
    for (int c = 0; c < 4; ++c)
#pragma unroll
      for (int q = 0; q < 4; ++q) {
        const int t = c * 128 + q * 32 + lane_t;
        S[(size_t)row * N + t] = __expf(l[c * 4 + q] - m) * inv;
      }
  }
}

// ---------------------------------------------------------------------------
extern "C" void kernel_launch(void* const* d_in, const int* in_sizes, int n_in,
                              void* d_out, int out_size, void* d_ws, size_t ws_size,
                              hipStream_t stream) {
  const float* x_s  = (const float*)d_in[0];
  const int*   ei_s = (const int*)d_in[1];
  const float* ea_s = (const float*)d_in[2];
  const float* x_t  = (const float*)d_in[4];
  const int*   ei_t = (const int*)d_in[5];
  const float* ea_t = (const float*)d_in[6];
  const float* r_all = (const float*)d_in[8];
  const float* W1r = (const float*)d_in[9];
  const float* W1n = (const float*)d_in[10];
  const float* b1  = (const float*)d_in[11];
  const float* W2r = (const float*)d_in[12];
  const float* W2n = (const float*)d_in[13];
  const float* b2  = (const float*)d_in[14];
  const float* Wm1 = (const float*)d_in[15];
  const float* bm1 = (const float*)d_in[16];
  const float* Wm2 = (const float*)d_in[17];
  const float* bm2 = (const float*)d_in[18];

  const int* src_s = ei_s;
  const int* dst_s = ei_s + E;
  const int* src_t = ei_t;
  const int* dst_t = ei_t + E;

  float* ws = (float*)d_ws;
  float* xr   = ws; ws += (size_t)2 * NT * D_H;
  float* xn   = ws; ws += (size_t)2 * NT * D_H;
  float* h    = ws; ws += (size_t)2 * NT * D_H;
  float* Shat = ws; ws += NN;
  float* rt_p = ws; ws += (size_t)8 * NT * R_IN;
  float* rt_b = ws; ws += (size_t)NT * R_IN;
  float* Psb  = ws; ws += (size_t)2 * NT * R_OUT;
  float* Ptb  = ws; ws += (size_t)NT * R_OUT;
  float* rowM = ws; ws += NT;
  float* rowI = ws; ws += NT;
  int* deg      = (int*)ws; ws += 2 * NT;
  int2* pack_s  = (int2*)ws; ws += (size_t)NT * CAP * 2;
  int2* pack_t  = (int2*)ws; ws += (size_t)NT * CAP * 2;

  float* S0_out = (float*)d_out;
  float* SL_out = S0_out + NN;

  // setup
  hipMemsetAsync(deg, 0, 2 * NT * sizeof(int), stream);
  setup_pack<<<768, 256, 0, stream>>>(src_s, dst_s, ea_s, src_t, dst_t, ea_t,
                                      deg, pack_s, pack_t,
                                      x_s, x_t, W1r, W1n, b1, xr, xn);
  agg_pack<<<1536, 256, 0, stream>>>(xn, xr, deg, pack_s, pack_t, h,
                                     r_all, W2r, W2n, b2, Wm1, bm1, Psb);
  gemm_sm<<<256, 512, 0, stream>>>(h, Shat, S0_out);

  // step 0
  rt_part_k<0><<<dim3(16, 8, B), 256, 0, stream>>>(S0_out, nullptr, nullptr, r_all, rt_p);
  rt_reduce8<<<128, 256, 0, stream>>>(rt_p, rt_b);
  gp2t<<<512, 256, 0, stream>>>(rt_b, deg + NT, pack_t, W2r, W2n, b2, Wm1, bm1, Ptb);
  update_sm2<0><<<512, 256, 0, stream>>>(Psb, Ptb, Wm2, bm2, Shat, nullptr, rowM, rowI);

  // step 1
  rt_part_k<1><<<dim3(16, 8, B), 256, 0, stream>>>(Shat, rowM, rowI,
                                                   r_all + (size_t)NT * R_IN, rt_p);
  rt_reduce8<<<128, 256, 0, stream>>>(rt_p, rt_b);
  gp2t<<<512, 256, 0, stream>>>(rt_b, deg + NT, pack_t, W2r, W2n, b2, Wm1, bm1, Ptb);
  update_sm2<1><<<512, 256, 0, stream>>>(Psb + (size_t)NT * R_OUT, Ptb, Wm2, bm2,
                                         Shat, SL_out, nullptr, nullptr);
}